// Round 10
// baseline (240.944 us; speedup 1.0000x reference)
//
#include <hip/hip_runtime.h>
#include <hip/hip_bf16.h>

// Problem constants
constexpr int B_ = 512;
constexpr int T_ = 128;
constexpr int D_ = 768;
constexpr int CD_ = 192;
constexpr int SD_ = 128;
constexpr int P_ = 128;
constexpr int FEAT_ = 321;   // CD + SD + 1
constexpr float LN_EPS_ = 1e-5f;

constexpr size_t REP_SZ   = (size_t)B_ * 2 * D_;     // 786432 floats
constexpr size_t DN16_FLT = (size_t)P_ * D_ / 2;     // 49152 floats

typedef __attribute__((ext_vector_type(8))) short short8;   // 8 bf16 (4 VGPRs)
typedef __attribute__((ext_vector_type(4))) float f32x4;
typedef unsigned long long ull_t;

__device__ __forceinline__ unsigned short f2bf(float x) {
    unsigned u = __float_as_uint(x);
    return (unsigned short)((u + 0x7FFFu + ((u >> 16) & 1u)) >> 16);
}
__device__ __forceinline__ float bf2f(unsigned short h) {
    return __uint_as_float((unsigned)h << 16);
}

// ---------------------------------------------------------------------------
// Kernel 1: dirs_n = dirs / ||dirs||, bf16 (plain row-major; read per-lane)
// ---------------------------------------------------------------------------
__global__ __launch_bounds__(256) void k_dirs(const float* __restrict__ dirs,
                                              unsigned short* __restrict__ dn16) {
    int p = blockIdx.x;
    int tid = threadIdx.x;
    float s = 0.f;
    for (int d = tid; d < D_; d += 256) {
        float v = dirs[(size_t)p * D_ + d];
        s = fmaf(v, v, s);
    }
    __shared__ float red[256];
    red[tid] = s;
    __syncthreads();
    for (int off = 128; off > 0; off >>= 1) {
        if (tid < off) red[tid] += red[tid + off];
        __syncthreads();
    }
    float inv = 1.0f / sqrtf(red[0]);
    for (int d = tid; d < D_; d += 256) {
        dn16[(size_t)p * D_ + d] = f2bf(dirs[(size_t)p * D_ + d] * inv);
    }
}

// ---------------------------------------------------------------------------
// Kernel 2: k_projfull — barrier-free register-direct MFMA GEMM
//   proj^T[p][t] = sum_d dn[p][d] * H[t][d]   (A=dn bf16 direct, B=H fp32->bf16)
// + fused rep (fp32, register partials + fr-shuffle + LDS k0-slices)
// + key-rank + paired diff + d_ot.   One 512-thread block per batch.
// ---------------------------------------------------------------------------
constexpr int NIT_ = 24;            // 768 / 32

__global__ __launch_bounds__(512) void k_projfull(const float* __restrict__ H,
                                                  const int* __restrict__ tt,
                                                  const int* __restrict__ attn,
                                                  const unsigned short* __restrict__ dn16,
                                                  float* __restrict__ rep,
                                                  float* __restrict__ d_ot) {
    const int b = blockIdx.x;
    const int tid = threadIdx.x;
    const int lane = tid & 63;
    const int w = tid >> 6;           // wave 0..7
    const int wp = w >> 2;            // p-half (output rows)
    const int wt = w & 3;             // t-quarter (output cols)
    const int fr = lane & 15;
    const int kg = lane >> 4;

    __shared__ __align__(16) unsigned short proj16[128 * 128];  // 32 KB (repP overlay during GEMM)
    __shared__ unsigned char xb[64 * 128];                      // 8 KB
    __shared__ unsigned char yb[64 * 128];                      // 8 KB
    __shared__ float dred[512];                                 // 2 KB (+ ballot exchange)
    __shared__ unsigned char pos_s[T_];
    float* repP = (float*)proj16;     // [24 it][4 wt][32 d][2 grp] = 24 KB

    // --- phase 0: masks via ballot, counts, pos map ---
    const int myt = 64 * wp + lane;
    int vt = tt[b * T_ + myt];
    int va = attn[b * T_ + myt];
    bool m0 = (vt == 0) && (va == 1);
    bool m1 = (vt == 1) && (va == 1);
    ull_t bal0 = __ballot(m0);
    ull_t bal1 = __ballot(m1);
    ull_t* xch = (ull_t*)dred;
    if (lane == 0 && (w == 0 || w == 4)) {
        xch[wp * 2] = bal0;
        xch[wp * 2 + 1] = bal1;
    }
    __syncthreads();
    const ull_t lo0 = xch[0], lo1 = xch[1], hi0 = xch[2], hi1 = xch[3];
    const int n0 = __popcll(lo0) + __popcll(hi0);
    const int n1 = __popcll(lo1) + __popcll(hi1);
    const int ntot = n0 + n1;
    const float inv0 = 1.f / (float)max(n0, 1);
    const float inv1 = 1.f / (float)max(n1, 1);
    ull_t below = (1ull << lane) - 1ull;
    int mypos = 0xFF;
    if (m0) mypos = (wp ? __popcll(lo0) : 0) + __popcll((wp ? hi0 : lo0) & below);
    else if (m1) mypos = n0 + (wp ? __popcll(lo1) : 0) + __popcll((wp ? hi1 : lo1) & below);
    if (w == 0 || w == 4) pos_s[myt] = (unsigned char)mypos;  // ordered by post-GEMM barrier

    // masks (fp32) for this thread's two B-frag rows
    const int t0 = 32 * wt + fr;      // n = 0
    const int t1 = t0 + 16;           // n = 1
    const float fm00 = (float)(((t0 < 64 ? lo0 >> t0 : hi0 >> (t0 - 64))) & 1ull);
    const float fm01 = (float)(((t1 < 64 ? lo0 >> t1 : hi0 >> (t1 - 64))) & 1ull);
    const float fm10 = (float)(((t0 < 64 ? lo1 >> t0 : hi1 >> (t0 - 64))) & 1ull);
    const float fm11 = (float)(((t1 < 64 ? lo1 >> t1 : hi1 >> (t1 - 64))) & 1ull);

    // --- phase 1: barrier-free GEMM + rep partials ---
    const float* Hb = H + (size_t)b * T_ * D_;
    const float* gB0 = Hb + (size_t)t0 * D_ + kg * 8;
    const float* gB1 = Hb + (size_t)t1 * D_ + kg * 8;
    const unsigned short* gA = dn16 + (size_t)(64 * wp + fr) * D_ + kg * 8;
    float* repb = rep + (size_t)b * 2 * D_;

    f32x4 acc[4][2];
#pragma unroll
    for (int m = 0; m < 4; ++m)
#pragma unroll
        for (int n = 0; n < 2; ++n) acc[m][n] = (f32x4){0.f, 0.f, 0.f, 0.f};

    for (int it = 0; it < NIT_; ++it) {
        const int k0 = it * 32;
        short8 a0 = *reinterpret_cast<const short8*>(gA + k0);
        short8 a1 = *reinterpret_cast<const short8*>(gA + 16 * D_ + k0);
        short8 a2 = *reinterpret_cast<const short8*>(gA + 32 * D_ + k0);
        short8 a3 = *reinterpret_cast<const short8*>(gA + 48 * D_ + k0);
        float4 h00 = *reinterpret_cast<const float4*>(gB0 + k0);
        float4 h01 = *reinterpret_cast<const float4*>(gB0 + k0 + 4);
        float4 h10 = *reinterpret_cast<const float4*>(gB1 + k0);
        float4 h11 = *reinterpret_cast<const float4*>(gB1 + k0 + 4);

        if (wp == 0) {    // rep partials (fp32): 4 waves cover all 128 t-rows
            float p0[8], p1[8];
            float h0v[8] = {h00.x, h00.y, h00.z, h00.w, h01.x, h01.y, h01.z, h01.w};
            float h1v[8] = {h10.x, h10.y, h10.z, h10.w, h11.x, h11.y, h11.z, h11.w};
#pragma unroll
            for (int j = 0; j < 8; ++j) {
                p0[j] = h0v[j] * fm00 + h1v[j] * fm01;
                p1[j] = h0v[j] * fm10 + h1v[j] * fm11;
            }
#pragma unroll
            for (int off = 1; off < 16; off <<= 1) {
#pragma unroll
                for (int j = 0; j < 8; ++j) {
                    p0[j] += __shfl_xor(p0[j], off);
                    p1[j] += __shfl_xor(p1[j], off);
                }
            }
            if (fr == 0) {   // lanes 0,16,32,48: dims kg*8..kg*8+7 of this k-chunk
                float* dst = repP + (it * 4 + wt) * 64 + kg * 16;
                *reinterpret_cast<float4*>(dst)      = (float4){p0[0], p1[0], p0[1], p1[1]};
                *reinterpret_cast<float4*>(dst + 4)  = (float4){p0[2], p1[2], p0[3], p1[3]};
                *reinterpret_cast<float4*>(dst + 8)  = (float4){p0[4], p1[4], p0[5], p1[5]};
                *reinterpret_cast<float4*>(dst + 12) = (float4){p0[6], p1[6], p0[7], p1[7]};
            }
        }

        short8 b0, b1;
        b0[0] = (short)f2bf(h00.x); b0[1] = (short)f2bf(h00.y);
        b0[2] = (short)f2bf(h00.z); b0[3] = (short)f2bf(h00.w);
        b0[4] = (short)f2bf(h01.x); b0[5] = (short)f2bf(h01.y);
        b0[6] = (short)f2bf(h01.z); b0[7] = (short)f2bf(h01.w);
        b1[0] = (short)f2bf(h10.x); b1[1] = (short)f2bf(h10.y);
        b1[2] = (short)f2bf(h10.z); b1[3] = (short)f2bf(h10.w);
        b1[4] = (short)f2bf(h11.x); b1[5] = (short)f2bf(h11.y);
        b1[6] = (short)f2bf(h11.z); b1[7] = (short)f2bf(h11.w);

        acc[0][0] = __builtin_amdgcn_mfma_f32_16x16x32_bf16(a0, b0, acc[0][0], 0, 0, 0);
        acc[0][1] = __builtin_amdgcn_mfma_f32_16x16x32_bf16(a0, b1, acc[0][1], 0, 0, 0);
        acc[1][0] = __builtin_amdgcn_mfma_f32_16x16x32_bf16(a1, b0, acc[1][0], 0, 0, 0);
        acc[1][1] = __builtin_amdgcn_mfma_f32_16x16x32_bf16(a1, b1, acc[1][1], 0, 0, 0);
        acc[2][0] = __builtin_amdgcn_mfma_f32_16x16x32_bf16(a2, b0, acc[2][0], 0, 0, 0);
        acc[2][1] = __builtin_amdgcn_mfma_f32_16x16x32_bf16(a2, b1, acc[2][1], 0, 0, 0);
        acc[3][0] = __builtin_amdgcn_mfma_f32_16x16x32_bf16(a3, b0, acc[3][0], 0, 0, 0);
        acc[3][1] = __builtin_amdgcn_mfma_f32_16x16x32_bf16(a3, b1, acc[3][1], 0, 0, 0);
    }
    __syncthreads();   // repP complete; pos_s visible

    // --- rep finalize: sum 4 wt-slices per dim, scale, store ---
    for (int i = tid; i < D_; i += 512) {
        int k0i = i >> 5, dl = i & 31;
        const float* src = repP + (k0i * 4) * 64 + dl * 2;
        float s0 = src[0] + src[64] + src[128] + src[192];
        float s1 = src[1] + src[65] + src[129] + src[193];
        repb[D_ + i] = s0 * inv0 - s1 * inv1;
    }
    if (tid < 192) {   // cls = H[b,0,:] exact fp32 (L2-hot)
        float4 v = *reinterpret_cast<const float4*>(Hb + tid * 4);
        *reinterpret_cast<float4*>(repb + tid * 4) = v;
    }
    __syncthreads();   // repP reads done before proj16 overwrite

    // --- epilogue: proj16[pos[t]][p] as sortable u16 ---
    const int pp0 = pos_s[t0];
    const int pp1 = pos_s[t1];
#pragma unroll
    for (int m = 0; m < 4; ++m) {
        int prow = 64 * wp + 16 * m + kg * 4;
#pragma unroll
        for (int r = 0; r < 4; ++r) {
            if (pp0 != 0xFF) {
                unsigned bb = f2bf(acc[m][0][r]);
                unsigned su = bb ^ ((bb >> 15) ? 0xFFFFu : 0x8000u);
                proj16[pp0 * 128 + prow + r] = (unsigned short)su;
            }
            if (pp1 != 0xFF) {
                unsigned bb = f2bf(acc[m][1][r]);
                unsigned su = bb ^ ((bb >> 15) ? 0xFFFFu : 0x8000u);
                proj16[pp1 * 128 + prow + r] = (unsigned short)su;
            }
        }
    }
    __syncthreads();

    // --- phase 2: ranking via sortable-u32 keys, single pass x 32 keys ---
    const int mmv = min(n0, n1);      // <= 64
    const int c = tid & 127;
    const int q = tid >> 7;           // 0..3
    const int pbase = q * 32;
    {
        unsigned kv[32];
        int cnt[32];
#pragma unroll
        for (int ii = 0; ii < 32; ++ii) {
            int p = pbase + ii;
            unsigned key = 0xFFFFFFFFu;
            if (p < ntot) {
                unsigned su = proj16[p * 128 + c];
                key = ((unsigned)(p >= n0) << 31) | (su << 8) | (unsigned)p;
            }
            kv[ii] = key;
            cnt[ii] = 0;
        }
        int lo, hi;
        if (pbase + 32 <= n0) { lo = 0;  hi = n0;   }
        else if (pbase >= n0) { lo = n0; hi = ntot; }
        else                  { lo = 0;  hi = ntot; }
        for (int j = lo; j < hi; ++j) {
            unsigned su = proj16[j * 128 + c];
            unsigned kw = ((unsigned)(j >= n0) << 31) | (su << 8) | (unsigned)j;
#pragma unroll
            for (int ii = 0; ii < 32; ++ii) cnt[ii] += (kw < kv[ii]) ? 1 : 0;
        }
#pragma unroll
        for (int ii = 0; ii < 32; ++ii) {
            int p = pbase + ii;
            if (p < ntot) {
                int rank = cnt[ii] - ((p >= n0 && lo == 0) ? n0 : 0);
                if (rank < mmv) {
                    unsigned char* buf = (p >= n0) ? yb : xb;
                    buf[rank * 128 + c] = (unsigned char)p;
                }
            }
        }
    }
    __syncthreads();

    // --- phase 3: paired diff per column, max over columns ---
    float part = 0.f;
    for (int r = q; r < mmv; r += 4) {
        unsigned sx = proj16[(int)xb[r * 128 + c] * 128 + c];
        unsigned sy = proj16[(int)yb[r * 128 + c] * 128 + c];
        unsigned bx = sx ^ ((sx >> 15) ? 0x8000u : 0xFFFFu);
        unsigned byv = sy ^ ((sy >> 15) ? 0x8000u : 0xFFFFu);
        part += fabsf(bf2f((unsigned short)bx) - bf2f((unsigned short)byv));
    }
    dred[tid] = part;
    __syncthreads();
    if (tid < 128) {
        float invm = 1.f / (float)max(mmv, 1);
        dred[tid] = (dred[tid] + dred[tid + 128] + dred[tid + 256] + dred[tid + 384]) * invm;
    }
    __syncthreads();
    if (tid < 64) {
        float m = fmaxf(dred[tid], dred[tid + 64]);
#pragma unroll
        for (int off = 32; off > 0; off >>= 1) m = fmaxf(m, __shfl_xor(m, off));
        if (tid == 0) d_ot[b] = m;
    }
}

// ---------------------------------------------------------------------------
// Kernel 3: head — C/S GEMV + gate + LayerNorm + logits.
// ---------------------------------------------------------------------------
__global__ __launch_bounds__(320) void k_head(const float* __restrict__ rep,
                                              const float* __restrict__ Wc,
                                              const float* __restrict__ bc,
                                              const float* __restrict__ Ws,
                                              const float* __restrict__ bs,
                                              const float* __restrict__ gate,
                                              const float* __restrict__ lng,
                                              const float* __restrict__ lnb,
                                              const float* __restrict__ Wcls,
                                              const float* __restrict__ bcls,
                                              const float* __restrict__ d_ot,
                                              float* __restrict__ out) {
    int b0 = blockIdx.x * 4;
    int tid = threadIdx.x;
    __shared__ __align__(16) float repS[4 * 1536];
    __shared__ float featS[4 * FEAT_];

    const float4* repg = reinterpret_cast<const float4*>(rep + (size_t)b0 * 1536);
    float4* repl = reinterpret_cast<float4*>(repS);
    for (int i = tid; i < 1536; i += 320) repl[i] = repg[i];
    __syncthreads();

    float g = 1.f / (1.f + expf(-gate[0]));

    {
        int o = tid;  // 0..319
        bool isC = o < CD_;
        const float* w = isC ? (Wc + (size_t)o * 1536) : (Ws + (size_t)(o - CD_) * 1536);
        float bias = isC ? bc[o] : bs[o - CD_];
        float scale = isC ? (1.f - g) : g;
        const float4* w4 = reinterpret_cast<const float4*>(w);
        float a0 = 0.f, a1 = 0.f, a2 = 0.f, a3 = 0.f;
        for (int k4 = 0; k4 < 384; ++k4) {
            float4 wv = w4[k4];
            float4 r0 = repl[k4];
            float4 r1 = repl[384 + k4];
            float4 r2 = repl[768 + k4];
            float4 r3 = repl[1152 + k4];
            a0 += fmaf(wv.x, r0.x, fmaf(wv.y, r0.y, fmaf(wv.z, r0.z, wv.w * r0.w)));
            a1 += fmaf(wv.x, r1.x, fmaf(wv.y, r1.y, fmaf(wv.z, r1.z, wv.w * r1.w)));
            a2 += fmaf(wv.x, r2.x, fmaf(wv.y, r2.y, fmaf(wv.z, r2.z, wv.w * r2.w)));
            a3 += fmaf(wv.x, r3.x, fmaf(wv.y, r3.y, fmaf(wv.z, r3.z, wv.w * r3.w)));
        }
        featS[0 * FEAT_ + o] = (a0 + bias) * scale;
        featS[1 * FEAT_ + o] = (a1 + bias) * scale;
        featS[2 * FEAT_ + o] = (a2 + bias) * scale;
        featS[3 * FEAT_ + o] = (a3 + bias) * scale;
    }
    if (tid < 4) featS[tid * FEAT_ + 320] = d_ot[b0 + tid];
    __syncthreads();

    int w = tid >> 6, lane = tid & 63;
    if (w < 4) {
        const float* f = featS + w * FEAT_;
        float s = 0.f, s2 = 0.f;
        for (int i = lane; i < FEAT_; i += 64) {
            float v = f[i];
            s += v;
            s2 = fmaf(v, v, s2);
        }
#pragma unroll
        for (int off = 32; off > 0; off >>= 1) {
            s += __shfl_xor(s, off);
            s2 += __shfl_xor(s2, off);
        }
        float mu = s * (1.f / (float)FEAT_);
        float var = fmaxf(s2 * (1.f / (float)FEAT_) - mu * mu, 0.f);
        float rstd = 1.0f / sqrtf(var + LN_EPS_);
        float l0 = 0.f, l1 = 0.f;
        for (int i = lane; i < FEAT_; i += 64) {
            float nv = (f[i] - mu) * rstd * lng[i] + lnb[i];
            l0 = fmaf(nv, Wcls[i], l0);
            l1 = fmaf(nv, Wcls[FEAT_ + i], l1);
        }
#pragma unroll
        for (int off = 32; off > 0; off >>= 1) {
            l0 += __shfl_xor(l0, off);
            l1 += __shfl_xor(l1, off);
        }
        if (lane == 0) {
            out[(size_t)(b0 + w) * 2 + 0] = l0 + bcls[0];
            out[(size_t)(b0 + w) * 2 + 1] = l1 + bcls[1];
        }
    }
}

// ---------------------------------------------------------------------------
// Kernel 4/5: ortho = mean((Wc @ Ws^T)^2)
// ---------------------------------------------------------------------------
__global__ __launch_bounds__(256) void k_ortho(const float* __restrict__ Wc,
                                               const float* __restrict__ Ws,
                                               float* __restrict__ part) {
    int i = blockIdx.x;
    int tid = threadIdx.x;
    __shared__ float wrow[1536];
    __shared__ float tmp[256];
    for (int k = tid; k < 1536; k += 256) wrow[k] = Wc[(size_t)i * 1536 + k];
    __syncthreads();
    int j = tid & 127, h = tid >> 7;
    const float* wsr = Ws + (size_t)j * 1536 + h * 768;
    const float* wr = wrow + h * 768;
    float s = 0.f;
    for (int k = 0; k < 768; ++k) s = fmaf(wr[k], wsr[k], s);
    tmp[tid] = s;
    __syncthreads();
    if (tid < 128) {
        float d = tmp[tid] + tmp[tid + 128];
        tmp[tid] = d * d;
    }
    __syncthreads();
    for (int off = 64; off > 0; off >>= 1) {
        if (tid < off) tmp[tid] += tmp[tid + off];
        __syncthreads();
    }
    if (tid == 0) part[i] = tmp[0];
}

__global__ __launch_bounds__(256) void k_ortho2(const float* __restrict__ part,
                                                float* __restrict__ out) {
    int tid = threadIdx.x;
    __shared__ float red[256];
    red[tid] = (tid < CD_) ? part[tid] : 0.f;
    __syncthreads();
    for (int off = 128; off > 0; off >>= 1) {
        if (tid < off) red[tid] += red[tid + off];
        __syncthreads();
    }
    if (tid == 0) out[(size_t)B_ * 2] = red[0] / (float)(CD_ * SD_);
}

// ---------------------------------------------------------------------------
extern "C" void kernel_launch(void* const* d_in, const int* in_sizes, int n_in,
                              void* d_out, int out_size, void* d_ws, size_t ws_size,
                              hipStream_t stream) {
    const float* H    = (const float*)d_in[0];
    const int*   tt   = (const int*)d_in[1];
    const int*   attn = (const int*)d_in[2];
    const float* Wc   = (const float*)d_in[3];
    const float* bc   = (const float*)d_in[4];
    const float* Ws   = (const float*)d_in[5];
    const float* bs   = (const float*)d_in[6];
    const float* gate = (const float*)d_in[7];
    const float* lng  = (const float*)d_in[8];
    const float* lnb  = (const float*)d_in[9];
    const float* Wcls = (const float*)d_in[10];
    const float* bcls = (const float*)d_in[11];
    const float* dirs = (const float*)d_in[12];

    float* ws    = (float*)d_ws;
    float* rep   = ws;                                      // [B][1536] fp32
    unsigned short* dn16 = (unsigned short*)(ws + REP_SZ);  // [P][D] bf16 (row-major)
    float* dot   = ws + REP_SZ + DN16_FLT;                  // [B]
    float* part  = dot + B_;                                // [CD]
    float* out   = (float*)d_out;

    k_dirs<<<P_, 256, 0, stream>>>(dirs, dn16);
    k_projfull<<<B_, 512, 0, stream>>>(H, tt, attn, dn16, rep, dot);
    k_head<<<B_ / 4, 320, 0, stream>>>(rep, Wc, bc, Ws, bs, gate, lng, lnb, Wcls, bcls, dot, out);
    k_ortho<<<CD_, 256, 0, stream>>>(Wc, Ws, part);
    k_ortho2<<<1, 256, 0, stream>>>(part, out);
}